// Round 1
// baseline (6887.406 us; speedup 1.0000x reference)
//
#include <hip/hip_runtime.h>
#include <math.h>

#define NTHREADS 256
#define IN_C 128
#define HID 64
#define OUT_C 40
#define N_LAYERS 8
#define ALPHA 0.1f
#define BN_EPS 1e-5f

// ---------------- setup kernels ----------------

__global__ void k_zero(int* __restrict__ cnt, float* __restrict__ sumP,
                       float* __restrict__ sumsqP, int n) {
  int i = blockIdx.x * NTHREADS + threadIdx.x;
  if (i < n) cnt[i] = 0;
  if (i < 1024) { sumP[i] = 0.f; sumsqP[i] = 0.f; }
}

__global__ void k_hist(const int* __restrict__ col, int* __restrict__ cnt, int E) {
  int e = blockIdx.x * NTHREADS + threadIdx.x;
  if (e < E) atomicAdd(&cnt[col[e]], 1);
}

// deg includes the self loop: deg[i] = cnt[i] + 1
__global__ void k_dinv(const int* __restrict__ cnt, float* __restrict__ dinv, int n) {
  int i = blockIdx.x * NTHREADS + threadIdx.x;
  if (i < n) dinv[i] = rsqrtf((float)cnt[i] + 1.0f);
}

// exclusive scan, pass 1: per-block scan of cnt -> block-local exclusive in offs, block total in partials
__global__ void k_scan1(const int* __restrict__ cnt, int* __restrict__ offs,
                        int* __restrict__ partials, int n) {
  __shared__ int sh[NTHREADS];
  int t = threadIdx.x, i = blockIdx.x * NTHREADS + t;
  int v = (i < n) ? cnt[i] : 0;
  sh[t] = v;
  __syncthreads();
  int run = v;
  for (int d = 1; d < NTHREADS; d <<= 1) {
    int add = (t >= d) ? sh[t - d] : 0;
    __syncthreads();
    run += add;
    sh[t] = run;
    __syncthreads();
  }
  if (i < n) offs[i] = run - v;          // exclusive within block
  if (t == NTHREADS - 1) partials[blockIdx.x] = run;  // block total
}

// pass 2: scan the (<=512) block totals in one block -> exclusive block offsets
__global__ void k_scan2(int* __restrict__ partials, int nb) {
  __shared__ int sh[512];
  int t = threadIdx.x;
  int v = (t < nb) ? partials[t] : 0;
  sh[t] = v;
  __syncthreads();
  int run = v;
  for (int d = 1; d < 512; d <<= 1) {
    int add = (t >= d) ? sh[t - d] : 0;
    __syncthreads();
    run += add;
    sh[t] = run;
    __syncthreads();
  }
  if (t < nb) partials[t] = run - v;     // exclusive
}

// pass 3: add block offsets; init fill cursors; set offs[n]=E
__global__ void k_scan3(int* __restrict__ offs, int* __restrict__ cur,
                        const int* __restrict__ partials, int n, int E) {
  int i = blockIdx.x * NTHREADS + threadIdx.x;
  if (i < n) {
    int v = offs[i] + partials[i >> 8];
    offs[i] = v;
    cur[i] = v;
  }
  if (i == 0) offs[n] = E;
}

// CSR fill: group source nodes by destination (col)
__global__ void k_fill(const int* __restrict__ row, const int* __restrict__ col,
                       int* __restrict__ cur, int* __restrict__ src, int E) {
  int e = blockIdx.x * NTHREADS + threadIdx.x;
  if (e < E) {
    int cl = col[e];
    int pos = atomicAdd(&cur[cl], 1);
    src[pos] = row[e];
  }
}

// ---------------- h = relu(x @ W0 + b0); also h0 = h ----------------
// block = 256 threads = 4 waves; block handles 8 rows; wave ty handles rows 2*ty, 2*ty+1
__global__ __launch_bounds__(NTHREADS) void k_gemm0(
    const float* __restrict__ x, const float* __restrict__ W0,
    const float* __restrict__ b0, float* __restrict__ h, float* __restrict__ h0,
    int n) {
  __shared__ float Ws[IN_C * HID];   // 32 KB
  __shared__ float xs[8 * IN_C];     // 4 KB
  int t = threadIdx.x;
  for (int m = t; m < IN_C * HID / 4; m += NTHREADS)
    ((float4*)Ws)[m] = ((const float4*)W0)[m];
  int gi = blockIdx.x * 256 + t;     // float4 index: 8 rows * 128 floats / 4 = 256 per block
  if (gi * 4 < n * IN_C) ((float4*)xs)[t] = ((const float4*)x)[gi];
  __syncthreads();
  int ty = t >> 6, c = t & 63;
  int r0 = blockIdx.x * 8 + ty * 2;
  float bias = b0[c];
  float acc0 = bias, acc1 = bias;
  const float4* xr0 = (const float4*)(xs + (ty * 2) * IN_C);
  const float4* xr1 = (const float4*)(xs + (ty * 2 + 1) * IN_C);
  for (int kk = 0; kk < IN_C / 4; kk++) {
    float4 a0 = xr0[kk], a1 = xr1[kk];
    int k = kk * 4;
    float w0 = Ws[(k + 0) * HID + c], w1 = Ws[(k + 1) * HID + c];
    float w2 = Ws[(k + 2) * HID + c], w3 = Ws[(k + 3) * HID + c];
    acc0 += a0.x * w0 + a0.y * w1 + a0.z * w2 + a0.w * w3;
    acc1 += a1.x * w0 + a1.y * w1 + a1.z * w2 + a1.w * w3;
  }
  acc0 = fmaxf(acc0, 0.f);
  acc1 = fmaxf(acc1, 0.f);
  if (r0 < n)     { h[(size_t)r0 * HID + c] = acc0; h0[(size_t)r0 * HID + c] = acc0; }
  if (r0 + 1 < n) { h[(size_t)(r0 + 1) * HID + c] = acc1; h0[(size_t)(r0 + 1) * HID + c] = acc1; }
}

// ---------------- fused layer: gather + residual + s@convW + BN stats ----------------
// block = 4 waves; per iteration block handles 16 nodes (wave wid handles 4 consecutive)
// lane c = channel. agg[i] = dinv[i] * ( sum_src dinv[src]*h[src] + dinv[i]*h[i] )
__global__ __launch_bounds__(NTHREADS) void k_layer(
    const float* __restrict__ h, const float* __restrict__ h0,
    const float* __restrict__ dinv, const int* __restrict__ offs,
    const int* __restrict__ src, const float* __restrict__ Wl,
    float* __restrict__ sout, float* __restrict__ sumP, float* __restrict__ sumsqP,
    float beta, int n) {
  __shared__ float Wsh[HID * HID];   // 16 KB, natural layout W[k][c]
  __shared__ float ss[16 * HID];     // 4 KB, 16 staged s-rows
  __shared__ float red[2 * NTHREADS];
  int t = threadIdx.x;
  for (int m = t; m < HID * HID / 4; m += NTHREADS)
    ((float4*)Wsh)[m] = ((const float4*)Wl)[m];
  __syncthreads();
  int wid = t >> 6, c = t & 63;
  float lsum = 0.f, lsumsq = 0.f;
  int stride = gridDim.x * 16;
  for (int base = blockIdx.x * 16; base < n; base += stride) {
    int i0 = base + wid * 4;
    float sv[4];
#pragma unroll
    for (int r = 0; r < 4; r++) {
      int i = i0 + r;
      float sval = 0.f;
      if (i < n) {
        float di = dinv[i];
        float acc = di * h[(size_t)i * HID + c];     // self loop
        int jb = offs[i], je = offs[i + 1];
        for (int j = jb; j < je; j++) {
          int sI = src[j];                            // wave-uniform
          acc += dinv[sI] * h[(size_t)sI * HID + c];  // coalesced 256B row read
        }
        float agg = di * acc;
        sval = (1.f - ALPHA) * agg + ALPHA * h0[(size_t)i * HID + c];
      }
      sv[r] = sval;
      ss[(wid * 4 + r) * HID + c] = sval;
    }
    __syncthreads();
    float ta0 = 0.f, ta1 = 0.f, ta2 = 0.f, ta3 = 0.f;
    const float4* s0 = (const float4*)(ss + (wid * 4 + 0) * HID);
    const float4* s1 = (const float4*)(ss + (wid * 4 + 1) * HID);
    const float4* s2 = (const float4*)(ss + (wid * 4 + 2) * HID);
    const float4* s3 = (const float4*)(ss + (wid * 4 + 3) * HID);
    for (int kk = 0; kk < HID / 4; kk++) {
      int k = kk * 4;
      float w0 = Wsh[(k + 0) * HID + c], w1 = Wsh[(k + 1) * HID + c];
      float w2 = Wsh[(k + 2) * HID + c], w3 = Wsh[(k + 3) * HID + c];
      float4 a;
      a = s0[kk]; ta0 += a.x * w0 + a.y * w1 + a.z * w2 + a.w * w3;
      a = s1[kk]; ta1 += a.x * w0 + a.y * w1 + a.z * w2 + a.w * w3;
      a = s2[kk]; ta2 += a.x * w0 + a.y * w1 + a.z * w2 + a.w * w3;
      a = s3[kk]; ta3 += a.x * w0 + a.y * w1 + a.z * w2 + a.w * w3;
    }
    float ta[4] = {ta0, ta1, ta2, ta3};
#pragma unroll
    for (int r = 0; r < 4; r++) {
      int i = i0 + r;
      if (i < n) {
        float s2v = (1.f - beta) * sv[r] + beta * ta[r];
        sout[(size_t)i * HID + c] = s2v;
        lsum += s2v;
        lsumsq += s2v * s2v;
      }
    }
    __syncthreads();   // protect ss before next iteration overwrites
  }
  // cross-wave reduce of BN partial sums, then one padded atomic per channel
  red[t] = lsum;
  red[NTHREADS + t] = lsumsq;
  __syncthreads();
  if (wid == 0) {
    float a = red[c] + red[64 + c] + red[128 + c] + red[192 + c];
    float b = red[NTHREADS + c] + red[NTHREADS + 64 + c] +
              red[NTHREADS + 128 + c] + red[NTHREADS + 192 + c];
    atomicAdd(&sumP[c * 16], a);      // 64B stride: one cache line per channel
    atomicAdd(&sumsqP[c * 16], b);
  }
}

// mean / inv-std; also resets the accumulators for the next layer
__global__ void k_finalize(float* __restrict__ sumP, float* __restrict__ sumsqP,
                           float* __restrict__ mstat, int n) {
  int c = threadIdx.x;  // 64 threads
  float s = sumP[c * 16], sq = sumsqP[c * 16];
  float mu = s / (float)n;
  float var = sq / (float)n - mu * mu;
  mstat[c] = mu;
  mstat[64 + c] = rsqrtf(var + BN_EPS);
  sumP[c * 16] = 0.f;
  sumsqP[c * 16] = 0.f;
}

// h = relu((s - mu) * inv * gamma + beta), float4-vectorized
__global__ void k_bnapply(const float* __restrict__ s, const float* __restrict__ mstat,
                          const float* __restrict__ gamma_l, const float* __restrict__ beta_l,
                          float* __restrict__ h, int n) {
  int idx = blockIdx.x * NTHREADS + threadIdx.x;  // float4 index
  if (idx < n * (HID / 4)) {
    int c4 = idx & 15;
    float4 v = ((const float4*)s)[idx];
    float4 mu = ((const float4*)mstat)[c4];
    float4 iv = ((const float4*)(mstat + 64))[c4];
    float4 g = ((const float4*)gamma_l)[c4];
    float4 b = ((const float4*)beta_l)[c4];
    v.x = fmaxf((v.x - mu.x) * iv.x * g.x + b.x, 0.f);
    v.y = fmaxf((v.y - mu.y) * iv.y * g.y + b.y, 0.f);
    v.z = fmaxf((v.z - mu.z) * iv.z * g.z + b.z, 0.f);
    v.w = fmaxf((v.w - mu.w) * iv.w * g.w + b.w, 0.f);
    ((float4*)h)[idx] = v;
  }
}

// out = h @ W_out + b_out  (one thread per output element)
__global__ __launch_bounds__(NTHREADS) void k_out(
    const float* __restrict__ h, const float* __restrict__ Wout,
    const float* __restrict__ bout, float* __restrict__ out, int n) {
  __shared__ float Ws[HID * OUT_C];  // 10 KB
  __shared__ float bs[OUT_C];
  int t = threadIdx.x;
  for (int m = t; m < HID * OUT_C; m += NTHREADS) Ws[m] = Wout[m];
  if (t < OUT_C) bs[t] = bout[t];
  __syncthreads();
  int idx = blockIdx.x * NTHREADS + t;
  if (idx < n * OUT_C) {
    int row = idx / OUT_C;
    int c = idx - row * OUT_C;
    float acc = bs[c];
    const float4* h4 = (const float4*)(h + (size_t)row * HID);
    for (int kk = 0; kk < HID / 4; kk++) {
      float4 a = h4[kk];
      int k = kk * 4;
      acc += a.x * Ws[(k + 0) * OUT_C + c] + a.y * Ws[(k + 1) * OUT_C + c] +
             a.z * Ws[(k + 2) * OUT_C + c] + a.w * Ws[(k + 3) * OUT_C + c];
    }
    out[idx] = acc;
  }
}

// ---------------- host ----------------

extern "C" void kernel_launch(void* const* d_in, const int* in_sizes, int n_in,
                              void* d_out, int out_size, void* d_ws, size_t ws_size,
                              hipStream_t stream) {
  const float* x = (const float*)d_in[0];
  const int* ei = (const int*)d_in[1];
  const float* W0 = (const float*)d_in[2];
  const float* b0 = (const float*)d_in[3];
  const float* convW = (const float*)d_in[4];
  const float* bn_gamma = (const float*)d_in[5];
  const float* bn_beta = (const float*)d_in[6];
  const float* W_out = (const float*)d_in[7];
  const float* b_out = (const float*)d_in[8];
  float* out = (float*)d_out;

  int n = in_sizes[0] / IN_C;   // 100000
  int E = in_sizes[1] / 2;      // 1600000
  const int* row = ei;
  const int* col = ei + E;

  char* w = (char*)d_ws;
  auto alloc = [&](size_t bytes) {
    char* p = w;
    w += (bytes + 255) & ~(size_t)255;
    return p;
  };
  float* dinv    = (float*)alloc((size_t)n * 4);
  int*   cnt     = (int*)alloc((size_t)n * 4);
  int*   offs    = (int*)alloc((size_t)(n + 1) * 4);
  int*   cur     = (int*)alloc((size_t)n * 4);
  int*   partials= (int*)alloc(512 * 4);
  int*   src     = (int*)alloc((size_t)E * 4);
  float* h0b     = (float*)alloc((size_t)n * HID * 4);
  float* hb      = (float*)alloc((size_t)n * HID * 4);
  float* sb      = (float*)alloc((size_t)n * HID * 4);
  float* sumP    = (float*)alloc(1024 * 4);
  float* sumsqP  = (float*)alloc(1024 * 4);
  float* mstat   = (float*)alloc(128 * 4);

  int gN = (n + NTHREADS - 1) / NTHREADS;   // 391
  int gE = (E + NTHREADS - 1) / NTHREADS;   // 6250

  k_zero<<<gN, NTHREADS, 0, stream>>>(cnt, sumP, sumsqP, n);
  k_hist<<<gE, NTHREADS, 0, stream>>>(col, cnt, E);
  k_dinv<<<gN, NTHREADS, 0, stream>>>(cnt, dinv, n);
  k_scan1<<<gN, NTHREADS, 0, stream>>>(cnt, offs, partials, n);
  k_scan2<<<1, 512, 0, stream>>>(partials, gN);
  k_scan3<<<gN, NTHREADS, 0, stream>>>(offs, cur, partials, n, E);
  k_fill<<<gE, NTHREADS, 0, stream>>>(row, col, cur, src, E);

  k_gemm0<<<(n + 7) / 8, NTHREADS, 0, stream>>>(x, W0, b0, hb, h0b, n);

  for (int l = 0; l < N_LAYERS; l++) {
    float beta = logf(0.5f / (float)(l + 1) + 1.0f);
    k_layer<<<2048, NTHREADS, 0, stream>>>(hb, h0b, dinv, offs, src,
                                           convW + (size_t)l * HID * HID, sb,
                                           sumP, sumsqP, beta, n);
    k_finalize<<<1, 64, 0, stream>>>(sumP, sumsqP, mstat, n);
    k_bnapply<<<(n * (HID / 4) + NTHREADS - 1) / NTHREADS, NTHREADS, 0, stream>>>(
        sb, mstat, bn_gamma + l * HID, bn_beta + l * HID, hb, n);
  }

  k_out<<<((size_t)n * OUT_C + NTHREADS - 1) / NTHREADS, NTHREADS, 0, stream>>>(
      hb, W_out, b_out, out, n);
}

// Round 2
// 3737.368 us; speedup vs baseline: 1.8428x; 1.8428x over previous
//
#include <hip/hip_runtime.h>
#include <math.h>

#define NTHREADS 256
#define IN_C 128
#define HID 64
#define OUT_C 40
#define N_LAYERS 8
#define ALPHA 0.1f
#define BN_EPS 1e-5f

// ---------------- setup kernels ----------------

__global__ void k_zero(int* __restrict__ cnt, float* __restrict__ sumP,
                       float* __restrict__ sumsqP, int n) {
  int i = blockIdx.x * NTHREADS + threadIdx.x;
  if (i < n) cnt[i] = 0;
  if (i < 1024) { sumP[i] = 0.f; sumsqP[i] = 0.f; }
}

__global__ void k_hist(const int* __restrict__ col, int* __restrict__ cnt, int E) {
  int e = blockIdx.x * NTHREADS + threadIdx.x;
  if (e < E) atomicAdd(&cnt[col[e]], 1);
}

// deg includes the self loop: deg[i] = cnt[i] + 1
__global__ void k_dinv(const int* __restrict__ cnt, float* __restrict__ dinv, int n) {
  int i = blockIdx.x * NTHREADS + threadIdx.x;
  if (i < n) dinv[i] = rsqrtf((float)cnt[i] + 1.0f);
}

// exclusive scan, pass 1
__global__ void k_scan1(const int* __restrict__ cnt, int* __restrict__ offs,
                        int* __restrict__ partials, int n) {
  __shared__ int sh[NTHREADS];
  int t = threadIdx.x, i = blockIdx.x * NTHREADS + t;
  int v = (i < n) ? cnt[i] : 0;
  sh[t] = v;
  __syncthreads();
  int run = v;
  for (int d = 1; d < NTHREADS; d <<= 1) {
    int add = (t >= d) ? sh[t - d] : 0;
    __syncthreads();
    run += add;
    sh[t] = run;
    __syncthreads();
  }
  if (i < n) offs[i] = run - v;
  if (t == NTHREADS - 1) partials[blockIdx.x] = run;
}

// pass 2: scan the (<=512) block totals
__global__ void k_scan2(int* __restrict__ partials, int nb) {
  __shared__ int sh[512];
  int t = threadIdx.x;
  int v = (t < nb) ? partials[t] : 0;
  sh[t] = v;
  __syncthreads();
  int run = v;
  for (int d = 1; d < 512; d <<= 1) {
    int add = (t >= d) ? sh[t - d] : 0;
    __syncthreads();
    run += add;
    sh[t] = run;
    __syncthreads();
  }
  if (t < nb) partials[t] = run - v;
}

// pass 3: add block offsets; init fill cursors; set offs[n]=E
__global__ void k_scan3(int* __restrict__ offs, int* __restrict__ cur,
                        const int* __restrict__ partials, int n, int E) {
  int i = blockIdx.x * NTHREADS + threadIdx.x;
  if (i < n) {
    int v = offs[i] + partials[i >> 8];
    offs[i] = v;
    cur[i] = v;
  }
  if (i == 0) offs[n] = E;
}

// CSR fill grouped by destination; packs {src, dinv[src]} into one 8B record
__global__ void k_fill(const int* __restrict__ row, const int* __restrict__ col,
                       const float* __restrict__ dinv, int* __restrict__ cur,
                       int2* __restrict__ ew, int E) {
  int e = blockIdx.x * NTHREADS + threadIdx.x;
  if (e < E) {
    int cl = col[e];
    int rw = row[e];
    int pos = atomicAdd(&cur[cl], 1);
    ew[pos] = make_int2(rw, __float_as_int(dinv[rw]));
  }
}

// ---------------- h = relu(x @ W0 + b0); also h0 = h ----------------
__global__ __launch_bounds__(NTHREADS) void k_gemm0(
    const float* __restrict__ x, const float* __restrict__ W0,
    const float* __restrict__ b0, float* __restrict__ h, float* __restrict__ h0,
    int n) {
  __shared__ float Ws[IN_C * HID];   // 32 KB
  __shared__ float xs[8 * IN_C];     // 4 KB
  int t = threadIdx.x;
  for (int m = t; m < IN_C * HID / 4; m += NTHREADS)
    ((float4*)Ws)[m] = ((const float4*)W0)[m];
  int gi = blockIdx.x * 256 + t;
  if (gi * 4 < n * IN_C) ((float4*)xs)[t] = ((const float4*)x)[gi];
  __syncthreads();
  int ty = t >> 6, c = t & 63;
  int r0 = blockIdx.x * 8 + ty * 2;
  float bias = b0[c];
  float acc0 = bias, acc1 = bias;
  const float4* xr0 = (const float4*)(xs + (ty * 2) * IN_C);
  const float4* xr1 = (const float4*)(xs + (ty * 2 + 1) * IN_C);
  for (int kk = 0; kk < IN_C / 4; kk++) {
    float4 a0 = xr0[kk], a1 = xr1[kk];
    int k = kk * 4;
    float w0 = Ws[(k + 0) * HID + c], w1 = Ws[(k + 1) * HID + c];
    float w2 = Ws[(k + 2) * HID + c], w3 = Ws[(k + 3) * HID + c];
    acc0 += a0.x * w0 + a0.y * w1 + a0.z * w2 + a0.w * w3;
    acc1 += a1.x * w0 + a1.y * w1 + a1.z * w2 + a1.w * w3;
  }
  acc0 = fmaxf(acc0, 0.f);
  acc1 = fmaxf(acc1, 0.f);
  if (r0 < n)     { h[(size_t)r0 * HID + c] = acc0; h0[(size_t)r0 * HID + c] = acc0; }
  if (r0 + 1 < n) { h[(size_t)(r0 + 1) * HID + c] = acc1; h0[(size_t)(r0 + 1) * HID + c] = acc1; }
}

// ---------------- fused layer: gather + residual + s@convW + BN stats ----------------
// block = 4 waves; per iteration block handles 16 nodes (wave wid handles 4).
// lane c = channel. Gather is 8-wide unrolled: 8 independent edge-record loads,
// then 8 independent h-row loads -> 2 latency waits per 8 edges instead of per edge.
__global__ __launch_bounds__(NTHREADS, 3) void k_layer(
    const float* __restrict__ h, const float* __restrict__ h0,
    const float* __restrict__ dinv, const int* __restrict__ offs,
    const int2* __restrict__ ew, const float* __restrict__ Wl,
    float* __restrict__ sout, float* __restrict__ sumP, float* __restrict__ sumsqP,
    float beta, int n) {
  __shared__ float Wsh[HID * HID];   // 16 KB
  __shared__ float ss[16 * HID];     // 4 KB
  __shared__ float red[2 * NTHREADS];
  int t = threadIdx.x;
  for (int m = t; m < HID * HID / 4; m += NTHREADS)
    ((float4*)Wsh)[m] = ((const float4*)Wl)[m];
  __syncthreads();
  int wid = t >> 6, c = t & 63;
  float lsum = 0.f, lsumsq = 0.f;
  int stride = gridDim.x * 16;
  for (int base = blockIdx.x * 16; base < n; base += stride) {
    int i0 = base + wid * 4;
    // gather phase: one row at a time (keeps register pressure low; MLP comes
    // from the 8-wide edge unroll)
    for (int r = 0; r < 4; r++) {
      int i = i0 + r;
      float sval = 0.f;
      if (i < n) {
        float di = dinv[i];
        float acc = di * h[(size_t)i * HID + c];     // self loop
        int jb = offs[i], je = offs[i + 1];
        int j = jb;
        for (; j + 8 <= je; j += 8) {
          int2 e0 = ew[j + 0], e1 = ew[j + 1], e2 = ew[j + 2], e3 = ew[j + 3];
          int2 e4 = ew[j + 4], e5 = ew[j + 5], e6 = ew[j + 6], e7 = ew[j + 7];
          float v0 = h[(size_t)e0.x * HID + c];
          float v1 = h[(size_t)e1.x * HID + c];
          float v2 = h[(size_t)e2.x * HID + c];
          float v3 = h[(size_t)e3.x * HID + c];
          float v4 = h[(size_t)e4.x * HID + c];
          float v5 = h[(size_t)e5.x * HID + c];
          float v6 = h[(size_t)e6.x * HID + c];
          float v7 = h[(size_t)e7.x * HID + c];
          acc += __int_as_float(e0.y) * v0 + __int_as_float(e1.y) * v1 +
                 __int_as_float(e2.y) * v2 + __int_as_float(e3.y) * v3;
          acc += __int_as_float(e4.y) * v4 + __int_as_float(e5.y) * v5 +
                 __int_as_float(e6.y) * v6 + __int_as_float(e7.y) * v7;
        }
        for (; j < je; j++) {
          int2 e = ew[j];
          acc += __int_as_float(e.y) * h[(size_t)e.x * HID + c];
        }
        float agg = di * acc;
        sval = (1.f - ALPHA) * agg + ALPHA * h0[(size_t)i * HID + c];
      }
      ss[(wid * 4 + r) * HID + c] = sval;
    }
    __syncthreads();
    // conv phase: ta[r] = (ss row r) @ Wl, column c per lane
    float ta0 = 0.f, ta1 = 0.f, ta2 = 0.f, ta3 = 0.f;
    const float4* s0 = (const float4*)(ss + (wid * 4 + 0) * HID);
    const float4* s1 = (const float4*)(ss + (wid * 4 + 1) * HID);
    const float4* s2 = (const float4*)(ss + (wid * 4 + 2) * HID);
    const float4* s3 = (const float4*)(ss + (wid * 4 + 3) * HID);
    for (int kk = 0; kk < HID / 4; kk++) {
      int k = kk * 4;
      float w0 = Wsh[(k + 0) * HID + c], w1 = Wsh[(k + 1) * HID + c];
      float w2 = Wsh[(k + 2) * HID + c], w3 = Wsh[(k + 3) * HID + c];
      float4 a;
      a = s0[kk]; ta0 += a.x * w0 + a.y * w1 + a.z * w2 + a.w * w3;
      a = s1[kk]; ta1 += a.x * w0 + a.y * w1 + a.z * w2 + a.w * w3;
      a = s2[kk]; ta2 += a.x * w0 + a.y * w1 + a.z * w2 + a.w * w3;
      a = s3[kk]; ta3 += a.x * w0 + a.y * w1 + a.z * w2 + a.w * w3;
    }
    float ta[4] = {ta0, ta1, ta2, ta3};
#pragma unroll
    for (int r = 0; r < 4; r++) {
      int i = i0 + r;
      if (i < n) {
        float sval = ss[(wid * 4 + r) * HID + c];
        float s2v = (1.f - beta) * sval + beta * ta[r];
        sout[(size_t)i * HID + c] = s2v;
        lsum += s2v;
        lsumsq += s2v * s2v;
      }
    }
    __syncthreads();
  }
  red[t] = lsum;
  red[NTHREADS + t] = lsumsq;
  __syncthreads();
  if (wid == 0) {
    float a = red[c] + red[64 + c] + red[128 + c] + red[192 + c];
    float b = red[NTHREADS + c] + red[NTHREADS + 64 + c] +
              red[NTHREADS + 128 + c] + red[NTHREADS + 192 + c];
    atomicAdd(&sumP[c * 16], a);
    atomicAdd(&sumsqP[c * 16], b);
  }
}

// mean / inv-std; resets accumulators for the next layer
__global__ void k_finalize(float* __restrict__ sumP, float* __restrict__ sumsqP,
                           float* __restrict__ mstat, int n) {
  int c = threadIdx.x;  // 64 threads
  float s = sumP[c * 16], sq = sumsqP[c * 16];
  float mu = s / (float)n;
  float var = sq / (float)n - mu * mu;
  mstat[c] = mu;
  mstat[64 + c] = rsqrtf(var + BN_EPS);
  sumP[c * 16] = 0.f;
  sumsqP[c * 16] = 0.f;
}

// h = relu((s - mu) * inv * gamma + beta), float4-vectorized
__global__ void k_bnapply(const float* __restrict__ s, const float* __restrict__ mstat,
                          const float* __restrict__ gamma_l, const float* __restrict__ beta_l,
                          float* __restrict__ h, int n) {
  int idx = blockIdx.x * NTHREADS + threadIdx.x;  // float4 index
  if (idx < n * (HID / 4)) {
    int c4 = idx & 15;
    float4 v = ((const float4*)s)[idx];
    float4 mu = ((const float4*)mstat)[c4];
    float4 iv = ((const float4*)(mstat + 64))[c4];
    float4 g = ((const float4*)gamma_l)[c4];
    float4 b = ((const float4*)beta_l)[c4];
    v.x = fmaxf((v.x - mu.x) * iv.x * g.x + b.x, 0.f);
    v.y = fmaxf((v.y - mu.y) * iv.y * g.y + b.y, 0.f);
    v.z = fmaxf((v.z - mu.z) * iv.z * g.z + b.z, 0.f);
    v.w = fmaxf((v.w - mu.w) * iv.w * g.w + b.w, 0.f);
    ((float4*)h)[idx] = v;
  }
}

// out = h @ W_out + b_out
__global__ __launch_bounds__(NTHREADS) void k_out(
    const float* __restrict__ h, const float* __restrict__ Wout,
    const float* __restrict__ bout, float* __restrict__ out, int n) {
  __shared__ float Ws[HID * OUT_C];
  __shared__ float bs[OUT_C];
  int t = threadIdx.x;
  for (int m = t; m < HID * OUT_C; m += NTHREADS) Ws[m] = Wout[m];
  if (t < OUT_C) bs[t] = bout[t];
  __syncthreads();
  int idx = blockIdx.x * NTHREADS + t;
  if (idx < n * OUT_C) {
    int row = idx / OUT_C;
    int c = idx - row * OUT_C;
    float acc = bs[c];
    const float4* h4 = (const float4*)(h + (size_t)row * HID);
    for (int kk = 0; kk < HID / 4; kk++) {
      float4 a = h4[kk];
      int k = kk * 4;
      acc += a.x * Ws[(k + 0) * OUT_C + c] + a.y * Ws[(k + 1) * OUT_C + c] +
             a.z * Ws[(k + 2) * OUT_C + c] + a.w * Ws[(k + 3) * OUT_C + c];
    }
    out[idx] = acc;
  }
}

// ---------------- host ----------------

extern "C" void kernel_launch(void* const* d_in, const int* in_sizes, int n_in,
                              void* d_out, int out_size, void* d_ws, size_t ws_size,
                              hipStream_t stream) {
  const float* x = (const float*)d_in[0];
  const int* ei = (const int*)d_in[1];
  const float* W0 = (const float*)d_in[2];
  const float* b0 = (const float*)d_in[3];
  const float* convW = (const float*)d_in[4];
  const float* bn_gamma = (const float*)d_in[5];
  const float* bn_beta = (const float*)d_in[6];
  const float* W_out = (const float*)d_in[7];
  const float* b_out = (const float*)d_in[8];
  float* out = (float*)d_out;

  int n = in_sizes[0] / IN_C;   // 100000
  int E = in_sizes[1] / 2;      // 1600000
  const int* row = ei;
  const int* col = ei + E;

  char* w = (char*)d_ws;
  auto alloc = [&](size_t bytes) {
    char* p = w;
    w += (bytes + 255) & ~(size_t)255;
    return p;
  };
  float* dinv    = (float*)alloc((size_t)n * 4);
  int*   cnt     = (int*)alloc((size_t)n * 4);
  int*   offs    = (int*)alloc((size_t)(n + 1) * 4);
  int*   cur     = (int*)alloc((size_t)n * 4);
  int*   partials= (int*)alloc(512 * 4);
  int2*  ew      = (int2*)alloc((size_t)E * 8);
  float* h0b     = (float*)alloc((size_t)n * HID * 4);
  float* hb      = (float*)alloc((size_t)n * HID * 4);
  float* sb      = (float*)alloc((size_t)n * HID * 4);
  float* sumP    = (float*)alloc(1024 * 4);
  float* sumsqP  = (float*)alloc(1024 * 4);
  float* mstat   = (float*)alloc(128 * 4);

  int gN = (n + NTHREADS - 1) / NTHREADS;   // 391
  int gE = (E + NTHREADS - 1) / NTHREADS;   // 6250

  k_zero<<<gN, NTHREADS, 0, stream>>>(cnt, sumP, sumsqP, n);
  k_hist<<<gE, NTHREADS, 0, stream>>>(col, cnt, E);
  k_dinv<<<gN, NTHREADS, 0, stream>>>(cnt, dinv, n);
  k_scan1<<<gN, NTHREADS, 0, stream>>>(cnt, offs, partials, n);
  k_scan2<<<1, 512, 0, stream>>>(partials, gN);
  k_scan3<<<gN, NTHREADS, 0, stream>>>(offs, cur, partials, n, E);
  k_fill<<<gE, NTHREADS, 0, stream>>>(row, col, dinv, cur, ew, E);

  k_gemm0<<<(n + 7) / 8, NTHREADS, 0, stream>>>(x, W0, b0, hb, h0b, n);

  for (int l = 0; l < N_LAYERS; l++) {
    float beta = logf(0.5f / (float)(l + 1) + 1.0f);
    k_layer<<<2048, NTHREADS, 0, stream>>>(hb, h0b, dinv, offs, ew,
                                           convW + (size_t)l * HID * HID, sb,
                                           sumP, sumsqP, beta, n);
    k_finalize<<<1, 64, 0, stream>>>(sumP, sumsqP, mstat, n);
    k_bnapply<<<(n * (HID / 4) + NTHREADS - 1) / NTHREADS, NTHREADS, 0, stream>>>(
        sb, mstat, bn_gamma + l * HID, bn_beta + l * HID, hb, n);
  }

  k_out<<<((size_t)n * OUT_C + NTHREADS - 1) / NTHREADS, NTHREADS, 0, stream>>>(
      hb, W_out, b_out, out, n);
}